// Round 1
// baseline (25178.723 us; speedup 1.0000x reference)
//
#include <hip/hip_runtime.h>
#include <math.h>

#define TSTEPS 512
#define NEX 256
#define NIN 128
#define HDIM 256

__device__ __forceinline__ float sigmoidf_(float x) {
    return 1.0f / (1.0f + expf(-x));
}

// One timestep. grid = (16,16): bx -> 16-unit tile, by -> 16-example tile.
// block = 256 threads: tx = tid&15 -> unit within tile, ty = tid>>4 -> example within tile.
// Each thread computes gates (i,f,g,o) for one (unit, example) pair: 4 dot products of K=384
// over Z = [h_prev(256) | x_t(128)], staged in LDS. W rows read directly from global (L2-resident).
__global__ __launch_bounds__(256) void lstm_step(
    const float* __restrict__ X,     // [256,128,512]
    const float* __restrict__ Wih,   // [1024,128]
    const float* __restrict__ Whh,   // [1024,256]
    const float* __restrict__ bias,  // [1024]
    float* __restrict__ A,           // [512,256,256]
    float* __restrict__ C,           // [512,256,256]
    int t)
{
    __shared__ float Zs[16][388];    // [ex_local][k]; stride 388 breaks stride-384 bank conflict
    const int tid = threadIdx.x;
    const int u0 = blockIdx.x * 16;
    const int e0 = blockIdx.y * 16;

    // ---- stage Z: h part (k < 256) ----
    if (t == 0) {
        for (int idx = tid; idx < 16 * 64; idx += 256) {
            const int exl = idx >> 6, q = idx & 63;
            float4* row = (float4*)&Zs[exl][0];
            row[q] = make_float4(0.f, 0.f, 0.f, 0.f);
        }
    } else {
        const float* Aprev = A + (size_t)(t - 1) * NEX * HDIM;
        for (int idx = tid; idx < 16 * 64; idx += 256) {
            const int exl = idx >> 6, q = idx & 63;
            float4* row = (float4*)&Zs[exl][0];
            row[q] = *(const float4*)(Aprev + (size_t)(e0 + exl) * HDIM + 4 * q);
        }
    }
    // ---- stage Z: x part (k in [256,384)) ----
    for (int idx = tid; idx < 16 * NIN; idx += 256) {
        const int exl = idx >> 7, i = idx & 127;
        Zs[exl][256 + i] = X[((size_t)(e0 + exl) * NIN + i) * TSTEPS + t];
    }
    __syncthreads();

    const int tx = tid & 15, ty = tid >> 4;
    const int u = u0 + tx;
    const int ex = e0 + ty;

    const float* w0 = Whh + (size_t)(0 * HDIM + u) * HDIM;
    const float* w1 = Whh + (size_t)(1 * HDIM + u) * HDIM;
    const float* w2 = Whh + (size_t)(2 * HDIM + u) * HDIM;
    const float* w3 = Whh + (size_t)(3 * HDIM + u) * HDIM;
    const float* v0 = Wih + (size_t)(0 * HDIM + u) * NIN;
    const float* v1 = Wih + (size_t)(1 * HDIM + u) * NIN;
    const float* v2 = Wih + (size_t)(2 * HDIM + u) * NIN;
    const float* v3 = Wih + (size_t)(3 * HDIM + u) * NIN;

    float acc0 = 0.f, acc1 = 0.f, acc2 = 0.f, acc3 = 0.f;
    const float* zrow = &Zs[ty][0];

    // h part: K = 256
#pragma unroll 8
    for (int k = 0; k < HDIM; k += 4) {
        const float4 z = *(const float4*)(zrow + k);
        const float4 a0 = *(const float4*)(w0 + k);
        const float4 a1 = *(const float4*)(w1 + k);
        const float4 a2 = *(const float4*)(w2 + k);
        const float4 a3 = *(const float4*)(w3 + k);
        acc0 += a0.x * z.x + a0.y * z.y + a0.z * z.z + a0.w * z.w;
        acc1 += a1.x * z.x + a1.y * z.y + a1.z * z.z + a1.w * z.w;
        acc2 += a2.x * z.x + a2.y * z.y + a2.z * z.z + a2.w * z.w;
        acc3 += a3.x * z.x + a3.y * z.y + a3.z * z.z + a3.w * z.w;
    }
    // x part: K = 128
#pragma unroll 8
    for (int k = 0; k < NIN; k += 4) {
        const float4 z = *(const float4*)(zrow + 256 + k);
        const float4 a0 = *(const float4*)(v0 + k);
        const float4 a1 = *(const float4*)(v1 + k);
        const float4 a2 = *(const float4*)(v2 + k);
        const float4 a3 = *(const float4*)(v3 + k);
        acc0 += a0.x * z.x + a0.y * z.y + a0.z * z.z + a0.w * z.w;
        acc1 += a1.x * z.x + a1.y * z.y + a1.z * z.z + a1.w * z.w;
        acc2 += a2.x * z.x + a2.y * z.y + a2.z * z.z + a2.w * z.w;
        acc3 += a3.x * z.x + a3.y * z.y + a3.z * z.z + a3.w * z.w;
    }

    // ---- pointwise LSTM cell ----
    const float gi = sigmoidf_(acc0 + 2.0f * bias[0 * HDIM + u]);
    const float gf = sigmoidf_(acc1 + 2.0f * bias[1 * HDIM + u]);
    const float gg = tanhf(acc2 + 2.0f * bias[2 * HDIM + u]);
    const float go = sigmoidf_(acc3 + 2.0f * bias[3 * HDIM + u]);

    const size_t off = (size_t)t * NEX * HDIM + (size_t)ex * HDIM + u;
    const float cprev = (t == 0) ? 0.f : C[off - (size_t)NEX * HDIM];
    const float cnew = gf * cprev + gi * gg;
    const float hnew = go * tanhf(cnew);
    A[off] = hnew;
    C[off] = cnew;
}

extern "C" void kernel_launch(void* const* d_in, const int* in_sizes, int n_in,
                              void* d_out, int out_size, void* d_ws, size_t ws_size,
                              hipStream_t stream) {
    const float* X   = (const float*)d_in[0];  // [256,128,512]
    const float* Wih = (const float*)d_in[1];  // [1024,128]
    const float* Whh = (const float*)d_in[2];  // [1024,256]
    const float* b   = (const float*)d_in[3];  // [1024]
    float* A = (float*)d_out;                          // [512,256,256]
    float* C = A + (size_t)TSTEPS * NEX * HDIM;        // [512,256,256]

    dim3 grid(16, 16);
    for (int t = 0; t < TSTEPS; ++t) {
        lstm_step<<<grid, 256, 0, stream>>>(X, Wih, Whh, b, A, C, t);
    }
}

// Round 2
// 7162.334 us; speedup vs baseline: 3.5154x; 3.5154x over previous
//
#include <hip/hip_runtime.h>
#include <math.h>

#define TSTEPS 512
#define NEX 256
#define NIN 128
#define HDIM 256
#define NCOLS 16          // example-columns (16 examples each)
#define NROWBLK 16        // unit-tile blocks per column

__device__ __forceinline__ float sigmoidf_(float x) {
    return 1.0f / (1.0f + expf(-x));
}

// Zero the sync flags (d_ws is poisoned 0xAA and not re-poisoned between replays).
__global__ void zero_flags(int* flags, int n) {
    int i = blockIdx.x * blockDim.x + threadIdx.x;
    if (i < n) flags[i] = 0;
}

// Persistent LSTM: 256 blocks = 16 unit-tiles x 16 example-columns, 1 block/CU.
// Block b: i = b>>4 (unit tile, u0 = i*16), j = b&15 (ex column, e0 = j*16).
// (b%8 == j%8 -> all 16 blocks of a column tend to share an XCD: locality hint only;
//  correctness uses agent-scope atomics for h-exchange regardless of placement.)
// Weights staged to LDS once; c carried in registers; h exchanged via agent atomics;
// per-(t,column) flag counters in d_ws gate the recurrence.
__global__ __launch_bounds__(256, 1) void lstm_persist(
    const float* __restrict__ X,     // [256,128,512]
    const float* __restrict__ Wih,   // [1024,128]
    const float* __restrict__ Whh,   // [1024,256]
    const float* __restrict__ bias,  // [1024]
    float* __restrict__ A,           // [512,256,256]
    float* __restrict__ C,           // [512,256,256]
    int* __restrict__ flags)         // [512*16]
{
    // Padded strides: multiples of 4 floats (16B-aligned rows) and stride%32==4 (bank spread).
    __shared__ float Whhs[64][260];  // 66.6 KB  rows: g*16+ul, g=gate, ul=unit_local
    __shared__ float Wihs[64][132];  // 33.8 KB
    __shared__ float Zs[16][388];    // 24.8 KB  [ex_local][ h(256) | x(128) ]
    __shared__ float bs[64];

    const int tid = threadIdx.x;
    const int b = blockIdx.x;
    const int i = b >> 4, j = b & 15;
    const int u0 = i * 16, e0 = j * 16;

    // ---- one-time weight staging ----
    for (int idx = tid; idx < 64 * 64; idx += 256) {        // Whh: 64 rows x 64 float4
        const int rl = idx >> 6, q = idx & 63;
        const int g = rl >> 4, ul = rl & 15;
        const float4 v = *(const float4*)(Whh + (size_t)(g * HDIM + u0 + ul) * HDIM + 4 * q);
        *(float4*)&Whhs[rl][4 * q] = v;
    }
    for (int idx = tid; idx < 64 * 32; idx += 256) {        // Wih: 64 rows x 32 float4
        const int rl = idx >> 5, q = idx & 31;
        const int g = rl >> 4, ul = rl & 15;
        const float4 v = *(const float4*)(Wih + (size_t)(g * HDIM + u0 + ul) * NIN + 4 * q);
        *(float4*)&Wihs[rl][4 * q] = v;
    }
    if (tid < 64) {
        const int g = tid >> 4, ul = tid & 15;
        bs[tid] = 2.0f * bias[g * HDIM + u0 + ul];
    }

    const int tx = tid & 15, ty = tid >> 4;   // tx -> unit_local, ty -> ex_local
    const int u = u0 + tx;
    const int ex = e0 + ty;
    float creg = 0.0f;

    __syncthreads();

    for (int t = 0; t < TSTEPS; ++t) {
        // ---- wait for h[t-1] of our 16 examples (written by 16 blocks of column j) ----
        if (t > 0) {
            if (tid == 0) {
                int* f = &flags[(t - 1) * NCOLS + j];
                while (__hip_atomic_load(f, __ATOMIC_RELAXED, __HIP_MEMORY_SCOPE_AGENT) < NROWBLK) {
                    __builtin_amdgcn_s_sleep(2);
                }
            }
            __syncthreads();
        }

        // ---- stage Z: h part (agent-scope loads: read-through to coherence point) ----
        if (t == 0) {
            for (int idx = tid; idx < 16 * HDIM; idx += 256) {
                Zs[idx >> 8][idx & 255] = 0.0f;
            }
        } else {
            const float* Aprev = A + (size_t)(t - 1) * NEX * HDIM;
            for (int idx = tid; idx < 16 * HDIM; idx += 256) {
                const int exl = idx >> 8, uu = idx & 255;
                Zs[exl][uu] = __hip_atomic_load(
                    (const float*)(Aprev + (size_t)(e0 + exl) * HDIM + uu),
                    __ATOMIC_RELAXED, __HIP_MEMORY_SCOPE_AGENT);
            }
        }
        // ---- stage Z: x part (normal cached loads; each 64B line serves 16 steps) ----
        for (int idx = tid; idx < 16 * NIN; idx += 256) {
            const int exl = idx >> 7, ii = idx & 127;
            Zs[exl][HDIM + ii] = X[((size_t)(e0 + exl) * NIN + ii) * TSTEPS + t];
        }
        __syncthreads();

        // ---- 4 gate dots (K=384) from LDS ----
        float acc0 = 0.f, acc1 = 0.f, acc2 = 0.f, acc3 = 0.f;
        const float* zrow = &Zs[ty][0];
#pragma unroll 8
        for (int k = 0; k < HDIM; k += 4) {
            const float4 z  = *(const float4*)(zrow + k);
            const float4 a0 = *(const float4*)&Whhs[0 * 16 + tx][k];
            const float4 a1 = *(const float4*)&Whhs[1 * 16 + tx][k];
            const float4 a2 = *(const float4*)&Whhs[2 * 16 + tx][k];
            const float4 a3 = *(const float4*)&Whhs[3 * 16 + tx][k];
            acc0 += a0.x * z.x + a0.y * z.y + a0.z * z.z + a0.w * z.w;
            acc1 += a1.x * z.x + a1.y * z.y + a1.z * z.z + a1.w * z.w;
            acc2 += a2.x * z.x + a2.y * z.y + a2.z * z.z + a2.w * z.w;
            acc3 += a3.x * z.x + a3.y * z.y + a3.z * z.z + a3.w * z.w;
        }
#pragma unroll 8
        for (int k = 0; k < NIN; k += 4) {
            const float4 z  = *(const float4*)(zrow + HDIM + k);
            const float4 a0 = *(const float4*)&Wihs[0 * 16 + tx][k];
            const float4 a1 = *(const float4*)&Wihs[1 * 16 + tx][k];
            const float4 a2 = *(const float4*)&Wihs[2 * 16 + tx][k];
            const float4 a3 = *(const float4*)&Wihs[3 * 16 + tx][k];
            acc0 += a0.x * z.x + a0.y * z.y + a0.z * z.z + a0.w * z.w;
            acc1 += a1.x * z.x + a1.y * z.y + a1.z * z.z + a1.w * z.w;
            acc2 += a2.x * z.x + a2.y * z.y + a2.z * z.z + a2.w * z.w;
            acc3 += a3.x * z.x + a3.y * z.y + a3.z * z.z + a3.w * z.w;
        }

        // ---- pointwise cell ----
        const float gi = sigmoidf_(acc0 + bs[0 * 16 + tx]);
        const float gf = sigmoidf_(acc1 + bs[1 * 16 + tx]);
        const float gg = tanhf(acc2 + bs[2 * 16 + tx]);
        const float go = sigmoidf_(acc3 + bs[3 * 16 + tx]);
        creg = gf * creg + gi * gg;
        const float hnew = go * tanhf(creg);

        const size_t off = (size_t)t * NEX * HDIM + (size_t)ex * HDIM + u;
        // h: agent-scope store (write-through to coherence point, cross-XCD visible)
        __hip_atomic_store(&A[off], hnew, __ATOMIC_RELAXED, __HIP_MEMORY_SCOPE_AGENT);
        C[off] = creg;  // never cross-read; flushed at kernel end

        // drain this wave's stores, then barrier, then publish
        asm volatile("s_waitcnt vmcnt(0)" ::: "memory");
        __syncthreads();
        if (tid == 0) {
            __hip_atomic_fetch_add(&flags[t * NCOLS + j], 1,
                                   __ATOMIC_RELAXED, __HIP_MEMORY_SCOPE_AGENT);
        }
    }
}

extern "C" void kernel_launch(void* const* d_in, const int* in_sizes, int n_in,
                              void* d_out, int out_size, void* d_ws, size_t ws_size,
                              hipStream_t stream) {
    const float* X   = (const float*)d_in[0];  // [256,128,512]
    const float* Wih = (const float*)d_in[1];  // [1024,128]
    const float* Whh = (const float*)d_in[2];  // [1024,256]
    const float* b   = (const float*)d_in[3];  // [1024]
    float* A = (float*)d_out;                           // [512,256,256]
    float* C = A + (size_t)TSTEPS * NEX * HDIM;         // [512,256,256]
    int* flags = (int*)d_ws;                            // [512*16]

    const int nflags = TSTEPS * NCOLS;
    zero_flags<<<(nflags + 255) / 256, 256, 0, stream>>>(flags, nflags);

    void* args[] = {(void*)&X, (void*)&Wih, (void*)&Whh, (void*)&b,
                    (void*)&A, (void*)&C, (void*)&flags};
    hipError_t err = hipLaunchCooperativeKernel((const void*)lstm_persist,
                                                dim3(256), dim3(256), args, 0, stream);
    if (err != hipSuccess) {
        // Fallback: plain launch. 125 KB LDS forces 1 block/CU; grid == CU count,
        // so all blocks co-resident in practice.
        lstm_persist<<<dim3(256), dim3(256), 0, stream>>>(X, Wih, Whh, b, A, C, flags);
    }
}

// Round 3
// 2421.546 us; speedup vs baseline: 10.3978x; 2.9578x over previous
//
#include <hip/hip_runtime.h>
#include <hip/hip_bf16.h>
#include <math.h>

#define TSTEPS 512
#define NEX 256
#define NIN 128
#define HDIM 256
#define NCOLS 16          // example-columns (16 examples each)
#define NROWBLK 16        // unit-tile blocks per column

typedef __attribute__((ext_vector_type(8))) short short8;   // 8 bf16 = 4 VGPRs (MFMA A/B frag)
typedef __attribute__((ext_vector_type(4))) float f32x4;    // MFMA C/D frag

__device__ __forceinline__ float sigmoidf_(float x) {
    return 1.0f / (1.0f + expf(-x));
}

__global__ void zero_flags(int* flags, int n) {
    int i = blockIdx.x * blockDim.x + threadIdx.x;
    if (i < n) flags[i] = 0;
}

// Persistent LSTM, MFMA edition. 256 blocks = 16 unit-tiles x 16 example-columns.
// Block b: i = b>>4 -> u0 = i*16 (units), j = b&15 -> e0 = j*16 (examples).
// Per step: D[16ex x 64 gate-rows] = Z[16 x 384] * W^T via mfma_f32_16x16x32_bf16,
// one gate per wave (4 waves). Weights staged once as bf16 in LDS. h exchanged fp32
// through A with agent-scope atomics + per-(t,column) flag counters (same as R2).
__global__ __launch_bounds__(256, 1) void lstm_persist(
    const float* __restrict__ X,     // [256,128,512]
    const float* __restrict__ Wih,   // [1024,128]
    const float* __restrict__ Whh,   // [1024,256]
    const float* __restrict__ bias,  // [1024]
    float* __restrict__ A,           // [512,256,256]
    float* __restrict__ C,           // [512,256,256]
    int* __restrict__ flags)         // [512*16]
{
    // Row stride 392 bf16 = 784 B: 16B-aligned rows, 784/4 % 32 = 4 -> bank-spread.
    __shared__ __align__(16) __hip_bfloat16 Ws[4][16][392]; // [gate][unit_local][k<384] 50.2 KB
    __shared__ __align__(16) __hip_bfloat16 Zs[16][392];    // [ex_local][ h(256)|x(128) ] 12.5 KB
    __shared__ float Gs[4][16][17];                         // [gate][ex_local][unit_local] 4.3 KB
    __shared__ float bs[64];                                // 2*bias, [gate*16+unit_local]

    const int tid = threadIdx.x;
    const int b = blockIdx.x;
    const int i = b >> 4, j = b & 15;
    const int u0 = i * 16, e0 = j * 16;

    // ---- one-time weight staging: fp32 -> bf16, [gate][ul][k] with k contiguous ----
    for (int idx = tid; idx < 64 * 96; idx += 256) {   // 64 rows x 96 float4 (64 Whh + 32 Wih)
        const int row = idx / 96, q = idx - row * 96;
        const int g = row >> 4, ul = row & 15;
        float4 v;
        int k0;
        if (q < 64) {
            v = *(const float4*)(Whh + (size_t)(g * HDIM + u0 + ul) * HDIM + 4 * q);
            k0 = 4 * q;
        } else {
            v = *(const float4*)(Wih + (size_t)(g * HDIM + u0 + ul) * NIN + 4 * (q - 64));
            k0 = HDIM + 4 * (q - 64);
        }
        Ws[g][ul][k0 + 0] = (__hip_bfloat16)v.x;
        Ws[g][ul][k0 + 1] = (__hip_bfloat16)v.y;
        Ws[g][ul][k0 + 2] = (__hip_bfloat16)v.z;
        Ws[g][ul][k0 + 3] = (__hip_bfloat16)v.w;
    }
    if (tid < 64) {
        const int g = tid >> 4, ul = tid & 15;
        bs[tid] = 2.0f * bias[g * HDIM + u0 + ul];
    }

    const int gw = tid >> 6;             // wave id == gate id
    const int l  = tid & 63;
    const int mrow = l & 15;             // A: ex_local ; B: unit_local ; D: unit col
    const int kg   = l >> 4;             // k-group (8 bf16 each)
    const int tx = tid & 15, ty = (tid >> 4) & 15;   // pointwise: (unit_local, ex_local)
    const int u = u0 + tx;
    const int ex = e0 + ty;
    float creg = 0.0f;

    __syncthreads();

    for (int t = 0; t < TSTEPS; ++t) {
        // ---- prefetch x[t] into registers (recurrence-independent; hides under spin) ----
        float xr[8];
#pragma unroll
        for (int s = 0; s < 8; ++s) {
            const int idx = tid + s * 256;           // 2048 = 16 ex x 128 inputs
            const int exl = idx >> 7, ii = idx & 127;
            xr[s] = X[((size_t)(e0 + exl) * NIN + ii) * TSTEPS + t];
        }

        // ---- wait for h[t-1] of our column ----
        if (t > 0) {
            if (tid == 0) {
                int* f = &flags[(t - 1) * NCOLS + j];
                while (__hip_atomic_load(f, __ATOMIC_RELAXED, __HIP_MEMORY_SCOPE_AGENT) < NROWBLK) {
                    __builtin_amdgcn_s_sleep(2);
                }
            }
            __syncthreads();
        }

        // ---- stage Z: h part (fp32 agent loads -> bf16) ----
        if (t == 0) {
            for (int idx = tid; idx < 16 * 64; idx += 256) {
                const int exl = idx >> 6, q = idx & 63;
                Zs[exl][4 * q + 0] = (__hip_bfloat16)0.0f;
                Zs[exl][4 * q + 1] = (__hip_bfloat16)0.0f;
                Zs[exl][4 * q + 2] = (__hip_bfloat16)0.0f;
                Zs[exl][4 * q + 3] = (__hip_bfloat16)0.0f;
            }
        } else {
            const float* Aprev = A + (size_t)(t - 1) * NEX * HDIM;
            for (int idx = tid; idx < 16 * 64; idx += 256) {
                const int exl = idx >> 6, q = idx & 63;
                const float* src = Aprev + (size_t)(e0 + exl) * HDIM + 4 * q;
                float v0 = __hip_atomic_load(src + 0, __ATOMIC_RELAXED, __HIP_MEMORY_SCOPE_AGENT);
                float v1 = __hip_atomic_load(src + 1, __ATOMIC_RELAXED, __HIP_MEMORY_SCOPE_AGENT);
                float v2 = __hip_atomic_load(src + 2, __ATOMIC_RELAXED, __HIP_MEMORY_SCOPE_AGENT);
                float v3 = __hip_atomic_load(src + 3, __ATOMIC_RELAXED, __HIP_MEMORY_SCOPE_AGENT);
                Zs[exl][4 * q + 0] = (__hip_bfloat16)v0;
                Zs[exl][4 * q + 1] = (__hip_bfloat16)v1;
                Zs[exl][4 * q + 2] = (__hip_bfloat16)v2;
                Zs[exl][4 * q + 3] = (__hip_bfloat16)v3;
            }
        }
        // ---- stage Z: x part from prefetched regs ----
#pragma unroll
        for (int s = 0; s < 8; ++s) {
            const int idx = tid + s * 256;
            const int exl = idx >> 7, ii = idx & 127;
            Zs[exl][HDIM + ii] = (__hip_bfloat16)xr[s];
        }
        __syncthreads();

        // ---- gate GEMM: wave gw computes D[16ex x 16unit] for gate gw, K=384 ----
        f32x4 acc = {0.f, 0.f, 0.f, 0.f};
#pragma unroll
        for (int kk = 0; kk < 12; ++kk) {
            const short8 afr = *(const short8*)&Zs[mrow][kk * 32 + kg * 8];
            const short8 bfr = *(const short8*)&Ws[gw][mrow][kk * 32 + kg * 8];
            acc = __builtin_amdgcn_mfma_f32_16x16x32_bf16(afr, bfr, acc, 0, 0, 0);
        }
        // D: col(l&15)=unit, row=(l>>4)*4+r=ex
#pragma unroll
        for (int r = 0; r < 4; ++r) {
            Gs[gw][kg * 4 + r][mrow] = acc[r];
        }
        __syncthreads();

        // ---- pointwise cell: thread (tx=unit, ty=ex) ----
        const float gi = sigmoidf_(Gs[0][ty][tx] + bs[0 * 16 + tx]);
        const float gf = sigmoidf_(Gs[1][ty][tx] + bs[1 * 16 + tx]);
        const float gg = tanhf(    Gs[2][ty][tx] + bs[2 * 16 + tx]);
        const float go = sigmoidf_(Gs[3][ty][tx] + bs[3 * 16 + tx]);
        creg = gf * creg + gi * gg;
        const float hnew = go * tanhf(creg);

        const size_t off = (size_t)t * NEX * HDIM + (size_t)ex * HDIM + u;
        __hip_atomic_store(&A[off], hnew, __ATOMIC_RELAXED, __HIP_MEMORY_SCOPE_AGENT);
        C[off] = creg;

        asm volatile("s_waitcnt vmcnt(0)" ::: "memory");
        __syncthreads();
        if (tid == 0) {
            __hip_atomic_fetch_add(&flags[t * NCOLS + j], 1,
                                   __ATOMIC_RELAXED, __HIP_MEMORY_SCOPE_AGENT);
        }
    }
}

extern "C" void kernel_launch(void* const* d_in, const int* in_sizes, int n_in,
                              void* d_out, int out_size, void* d_ws, size_t ws_size,
                              hipStream_t stream) {
    const float* X   = (const float*)d_in[0];  // [256,128,512]
    const float* Wih = (const float*)d_in[1];  // [1024,128]
    const float* Whh = (const float*)d_in[2];  // [1024,256]
    const float* b   = (const float*)d_in[3];  // [1024]
    float* A = (float*)d_out;                           // [512,256,256]
    float* C = A + (size_t)TSTEPS * NEX * HDIM;         // [512,256,256]
    int* flags = (int*)d_ws;                            // [512*16]

    const int nflags = TSTEPS * NCOLS;
    zero_flags<<<(nflags + 255) / 256, 256, 0, stream>>>(flags, nflags);

    void* args[] = {(void*)&X, (void*)&Wih, (void*)&Whh, (void*)&b,
                    (void*)&A, (void*)&C, (void*)&flags};
    hipError_t err = hipLaunchCooperativeKernel((const void*)lstm_persist,
                                                dim3(256), dim3(256), args, 0, stream);
    if (err != hipSuccess) {
        lstm_persist<<<dim3(256), dim3(256), 0, stream>>>(X, Wih, Whh, b, A, C, flags);
    }
}